// Round 13
// baseline (407.360 us; speedup 1.0000x reference)
//
#include <hip/hip_runtime.h>
#include <hip/hip_bf16.h>

// SolveGradientsLST: bucket binning with DETERMINISTIC offsets (zero global
// atomics) + within-bucket LDS counting sort + register accumulation.
// (3rd submission of the R11 design — infra timeouts; never executed.)
//
// R10 measured: KC(sort+reg-accum) 472->137us confirmed the R8 diagnosis
// (divergent row-gathers + 11x ds_add_f32 per edge were the invariant cost).
// Remaining 204us is KA/KB's ~1.9M global atomics on 977 hot addresses
// (~12G/s service rate, R3-measured). This round removes ALL global atomics:
//   KA' per-block LDS hist -> counts[blk][b] matrix (coalesced write)
//   KS1 per-bucket column exclusive scan over blocks (in place) + totals[b]
//   KS2 1-block exclusive scan of totals -> bucket_start[b]
//   KB' lbase[b] = bucket_start[b] + prefix[blk][b]; LDS rank atomics only
//   KC  CAP 8192 (38KB LDS -> 4 blocks/CU) + payload reg-cached across the
//       hist/scatter passes (static 16x unroll)
// Fallback to the R10-measured path if ws too small or nblk > 512.

#define GRAD_LIMIT 30000.0f
#define EPS 1e-8

#define NBUCKET_MAX 1024
#define BSHIFT 9
#define BSIZE 512                 // nodes per bucket == threads in KC
#define CHUNK 8192                // edges per block (fallback KA/KB)
#define BTHREADS 512
#define PER_THREAD (CHUNK / BTHREADS)   // 16 (fallback KB)
#define CHUNK_E 16384             // edges per block (new KA'/KB')
#define CAP 8192                  // sorted[] entries per KC chunk (32 KB)
#define KC_ITERS (CAP / BSIZE)    // 16

// ---------------- KP: build packed 32B node records ----------------
__global__ void pack_kernel(const float2* __restrict__ pos,
                            const float4* __restrict__ field,
                            float4* __restrict__ packed, int N) {
    int n = blockIdx.x * blockDim.x + threadIdx.x;
    if (n >= N) return;
    float2 p = pos[n];
    float4 f = field[n];
    packed[2 * n + 0] = make_float4(p.x, p.y, f.x, f.y);
    packed[2 * n + 1] = make_float4(f.z, f.w, 0.f, 0.f);
}

// ================= NEW PATH (no global atomics) =================

// KA': per-block histogram -> counts[blk][b] (coalesced row write)
__global__ void __launch_bounds__(BTHREADS)
count2_kernel(const int* __restrict__ rows, int* __restrict__ counts,
              int E, int nbuckets) {
    __shared__ int hist[NBUCKET_MAX];
    for (int i = threadIdx.x; i < nbuckets; i += blockDim.x) hist[i] = 0;
    __syncthreads();
    int base = blockIdx.x * CHUNK_E;
    int lim = E - base;
    if (lim > CHUNK_E) lim = CHUNK_E;
    for (int k = threadIdx.x; k < lim; k += blockDim.x)
        atomicAdd(&hist[rows[base + k] >> BSHIFT], 1);
    __syncthreads();
    int* row = counts + (size_t)blockIdx.x * nbuckets;
    for (int i = threadIdx.x; i < nbuckets; i += blockDim.x) row[i] = hist[i];
}

// KS1: per-bucket exclusive column scan over blocks, in place; totals[b].
// Requires nblk <= 512.
__global__ void __launch_bounds__(512)
colscan_kernel(int* __restrict__ counts, int* __restrict__ totals,
               int nblk, int nbuckets) {
    __shared__ int s[512];
    int b = blockIdx.x;
    int t = threadIdx.x;
    int v = (t < nblk) ? counts[(size_t)t * nbuckets + b] : 0;
    s[t] = v;
    __syncthreads();
    for (int d = 1; d < 512; d <<= 1) {
        int x = (t >= d) ? s[t - d] : 0;
        __syncthreads();
        s[t] += x;
        __syncthreads();
    }
    if (t < nblk) counts[(size_t)t * nbuckets + b] = s[t] - v;  // exclusive
    if (t == 511) totals[b] = s[511];
}

// KS2: single-block exclusive scan of totals -> bucket_start (nb <= 1024)
__global__ void totscan_kernel(const int* __restrict__ totals,
                               int* __restrict__ bucket_start, int nb) {
    __shared__ int s[1024];
    int t = threadIdx.x;
    int v = (t < nb) ? totals[t] : 0;
    s[t] = v;
    __syncthreads();
    for (int d = 1; d < 1024; d <<= 1) {
        int x = (t >= d) ? s[t - d] : 0;
        __syncthreads();
        s[t] += x;
        __syncthreads();
    }
    if (t < nb) bucket_start[t] = s[t] - v;
}

// KB': scatter with deterministic bases; LDS rank atomics only.
__global__ void __launch_bounds__(BTHREADS)
scatter2_kernel(const int* __restrict__ rows, const int* __restrict__ cols,
                const int* __restrict__ bucket_start,
                const int* __restrict__ counts,   // exclusive prefix per blk
                unsigned* __restrict__ payload, int E, int nbuckets) {
    __shared__ int rank[NBUCKET_MAX];
    __shared__ int lbase[NBUCKET_MAX];
    int blk = blockIdx.x;
    const int* pre = counts + (size_t)blk * nbuckets;
    for (int i = threadIdx.x; i < nbuckets; i += blockDim.x) {
        rank[i] = 0;
        lbase[i] = bucket_start[i] + pre[i];
    }
    __syncthreads();
    int base = blk * CHUNK_E;
    int lim = E - base;
    if (lim > CHUNK_E) lim = CHUNK_E;
    for (int k = threadIdx.x; k < lim; k += blockDim.x) {
        int e = base + k;
        int r = rows[e];
        int c = cols[e];
        int b = r >> BSHIFT;
        int lr = atomicAdd(&rank[b], 1);            // LDS returning atomic
        payload[lbase[b] + lr] =
            ((unsigned)(r & (BSIZE - 1)) << 19) | (unsigned)c;   // c < 2^19
    }
}

// ================= FALLBACK PATH (R10-measured) =================

__global__ void __launch_bounds__(BTHREADS)
bucket_count_kernel(const int* __restrict__ rows, int* __restrict__ bucket_cnt,
                    int E, int nbuckets) {
    __shared__ int hist[NBUCKET_MAX];
    for (int i = threadIdx.x; i < nbuckets; i += blockDim.x) hist[i] = 0;
    __syncthreads();
    int base = blockIdx.x * CHUNK;
    int lim = E - base;
    if (lim > CHUNK) lim = CHUNK;
    for (int k = threadIdx.x; k < lim; k += blockDim.x)
        atomicAdd(&hist[rows[base + k] >> BSHIFT], 1);
    __syncthreads();
    for (int i = threadIdx.x; i < nbuckets; i += blockDim.x) {
        int c = hist[i];
        if (c) atomicAdd(&bucket_cnt[i], c);
    }
}

__global__ void bucket_scan_kernel(const int* __restrict__ bucket_cnt,
                                   int* __restrict__ bucket_start,
                                   int* __restrict__ cursor, int nb) {
    __shared__ int s[NBUCKET_MAX];
    int t = threadIdx.x;
    int v = (t < nb) ? bucket_cnt[t] : 0;
    s[t] = v;
    __syncthreads();
    for (int d = 1; d < NBUCKET_MAX; d <<= 1) {
        int x = (t >= d) ? s[t - d] : 0;
        __syncthreads();
        s[t] += x;
        __syncthreads();
    }
    if (t < nb) {
        int ex = s[t] - v;
        bucket_start[t] = ex;
        cursor[t] = ex;
    }
}

__global__ void __launch_bounds__(BTHREADS)
bucket_scatter_kernel(const int* __restrict__ rows, const int* __restrict__ cols,
                      int* __restrict__ cursor, unsigned* __restrict__ payload,
                      int E, int nbuckets) {
    __shared__ int hist[NBUCKET_MAX];
    __shared__ int lbase[NBUCKET_MAX];
    for (int i = threadIdx.x; i < nbuckets; i += blockDim.x) hist[i] = 0;
    __syncthreads();
    int base = blockIdx.x * CHUNK;
    int lim = E - base;
    if (lim > CHUNK) lim = CHUNK;
    unsigned pk[PER_THREAD];
    int bl[PER_THREAD];
#pragma unroll
    for (int k = 0; k < PER_THREAD; ++k) {
        int idx = k * BTHREADS + threadIdx.x;
        if (idx < lim) {
            int e = base + idx;
            int r = rows[e];
            int c = cols[e];
            int b = r >> BSHIFT;
            int lr = atomicAdd(&hist[b], 1);
            pk[k] = ((unsigned)(r & (BSIZE - 1)) << 19) | (unsigned)c;
            bl[k] = (b << 13) | lr;
        } else {
            bl[k] = -1;
        }
    }
    __syncthreads();
    for (int i = threadIdx.x; i < nbuckets; i += blockDim.x) {
        int c = hist[i];
        lbase[i] = c ? atomicAdd(&cursor[i], c) : 0;
    }
    __syncthreads();
#pragma unroll
    for (int k = 0; k < PER_THREAD; ++k) {
        if (bl[k] >= 0) {
            int b = bl[k] >> 13;
            int lr = bl[k] & 8191;
            payload[lbase[b] + lr] = pk[k];
        }
    }
}

// ---------------- KC: within-bucket row sort + register accumulation ----
// s1 = bucket_start[b] + totals[b]
__global__ void __launch_bounds__(BSIZE)
bucket_sort_accum_solve(const float4* __restrict__ packed,
                        const int* __restrict__ bucket_start,
                        const int* __restrict__ totals,
                        const unsigned* __restrict__ payload,
                        float* __restrict__ out,  // [F,N,2]
                        int N) {
    __shared__ unsigned sorted[CAP];   // 32 KB
    __shared__ int hist[BSIZE];
    __shared__ int incl[BSIZE];
    __shared__ int cur[BSIZE];

    int t = threadIdx.x;
    int b = blockIdx.x;
    int node0 = b << BSHIFT;

    float4 ra = make_float4(0.f, 0.f, 0.f, 0.f);
    float4 rb = ra;
    if (node0 + t < N) {
        ra = packed[2 * (node0 + t) + 0];
        rb = packed[2 * (node0 + t) + 1];
    }

    float m00 = 0.f, m01 = 0.f, m11 = 0.f;
    float v00 = 0.f, v01 = 0.f, v02 = 0.f, v03 = 0.f;
    float v10 = 0.f, v11 = 0.f, v12 = 0.f, v13 = 0.f;

    int s0 = bucket_start[b];
    int s1 = s0 + totals[b];

    for (int cstart = s0; cstart < s1; cstart += CAP) {
        int cnt = s1 - cstart;
        if (cnt > CAP) cnt = CAP;

        hist[t] = 0;
        __syncthreads();

        // pass1: coalesced read, payload cached in registers (static unroll)
        unsigned pr[KC_ITERS];
#pragma unroll
        for (int it = 0; it < KC_ITERS; ++it) {
            int i = it * BSIZE + t;
            pr[it] = 0u;
            if (i < cnt) {
                pr[it] = payload[cstart + i];
                atomicAdd(&hist[pr[it] >> 19], 1);
            }
        }
        __syncthreads();

        // inclusive Hillis-Steele scan over 512
        incl[t] = hist[t];
        __syncthreads();
        for (int d = 1; d < BSIZE; d <<= 1) {
            int x = (t >= d) ? incl[t - d] : 0;
            __syncthreads();
            incl[t] += x;
            __syncthreads();
        }
        cur[t] = incl[t] - hist[t];
        __syncthreads();

        // pass2: scatter from registers into row-sorted LDS order
#pragma unroll
        for (int it = 0; it < KC_ITERS; ++it) {
            int i = it * BSIZE + t;
            if (i < cnt) {
                int k = atomicAdd(&cur[pr[it] >> 19], 1);
                sorted[k] = pr[it];
            }
        }
        __syncthreads();

        // pass3: thread t drains row t's contiguous range; col gathers only
        int st = incl[t] - hist[t];
        int en = incl[t];
        for (int k = st; k < en; ++k) {
            unsigned p = sorted[k];
            int c = (int)(p & 0x7FFFFu);
            float4 ca = packed[2 * c + 0];
            float4 cb = packed[2 * c + 1];
            float dx0 = ca.x - ra.x;
            float dx1 = ca.y - ra.y;
            float du0 = ca.z - ra.z;
            float du1 = ca.w - ra.w;
            float du2 = cb.x - rb.x;
            float du3 = cb.y - rb.y;
            m00 = fmaf(dx0, dx0, m00);
            m01 = fmaf(dx0, dx1, m01);
            m11 = fmaf(dx1, dx1, m11);
            v00 = fmaf(dx0, du0, v00);
            v01 = fmaf(dx0, du1, v01);
            v02 = fmaf(dx0, du2, v02);
            v03 = fmaf(dx0, du3, v03);
            v10 = fmaf(dx1, du0, v10);
            v11 = fmaf(dx1, du1, v11);
            v12 = fmaf(dx1, du2, v12);
            v13 = fmaf(dx1, du3, v13);
        }
        __syncthreads();
    }

    // f64 2x2 solve (f32 det is cancellation-dominated for low-degree nodes)
    int n = node0 + t;
    if (n >= N) return;
    double M00 = (double)m00 + EPS;
    double M01 = (double)m01;
    double M11 = (double)m11 + EPS;
    double inv_det = 1.0 / (M00 * M11 - M01 * M01);
    double i00 = M11 * inv_det;
    double i01 = -M01 * inv_det;
    double i11 = M00 * inv_det;

    const float vf0[4] = {v00, v01, v02, v03};
    const float vf1[4] = {v10, v11, v12, v13};
#pragma unroll
    for (int f = 0; f < 4; ++f) {
        float ga = (float)(i00 * (double)vf0[f] + i01 * (double)vf1[f]);
        float gb = (float)(i01 * (double)vf0[f] + i11 * (double)vf1[f]);
        float2 o;
        o.x = fminf(fmaxf(ga, -GRAD_LIMIT), GRAD_LIMIT);
        o.y = fminf(fmaxf(gb, -GRAD_LIMIT), GRAD_LIMIT);
        *reinterpret_cast<float2*>(out + (size_t)f * N * 2 + (size_t)n * 2) = o;
    }
}

extern "C" void kernel_launch(void* const* d_in, const int* in_sizes, int n_in,
                              void* d_out, int out_size, void* d_ws, size_t ws_size,
                              hipStream_t stream) {
    const float2* pos = (const float2*)d_in[0];
    const int* edge_index = (const int*)d_in[1];
    const float4* field = (const float4*)d_in[2];
    float* out = (float*)d_out;

    const int N = in_sizes[0] / 2;
    const int E = in_sizes[1] / 2;

    const int* rows = edge_index;      // edge_index[0, :]
    const int* cols = edge_index + E;  // edge_index[1, :]

    const int nbuckets = (N + BSIZE - 1) / BSIZE;        // 977
    const int nblk = (E + CHUNK_E - 1) / CHUNK_E;        // 489
    const int nblocksF = (E + CHUNK - 1) / CHUNK;        // 977 (fallback)

    size_t packed_bytes = (size_t)2 * N * sizeof(float4);              // 16 MB
    size_t counts_bytes = (size_t)nblk * nbuckets * sizeof(int);       // 1.9 MB
    size_t need_new = packed_bytes + (size_t)E * 4 + counts_bytes
                      + (size_t)2 * NBUCKET_MAX * 4;                   // ~50 MB

    if (ws_size >= need_new && nblk <= 512) {
        // Layout: packed | payload[E] | counts[nblk*nb] | totals | start
        float4* packed = (float4*)d_ws;
        unsigned* payload = (unsigned*)(packed + (size_t)2 * N);
        int* counts = (int*)(payload + (size_t)E);
        int* totals = counts + (size_t)nblk * nbuckets;
        int* bucket_start = totals + NBUCKET_MAX;

        pack_kernel<<<(N + 255) / 256, 256, 0, stream>>>(pos, field, packed, N);
        count2_kernel<<<nblk, BTHREADS, 0, stream>>>(rows, counts, E, nbuckets);
        colscan_kernel<<<nbuckets, 512, 0, stream>>>(counts, totals, nblk,
                                                     nbuckets);
        totscan_kernel<<<1, 1024, 0, stream>>>(totals, bucket_start, nbuckets);
        scatter2_kernel<<<nblk, BTHREADS, 0, stream>>>(rows, cols, bucket_start,
                                                       counts, payload, E,
                                                       nbuckets);
        bucket_sort_accum_solve<<<nbuckets, BSIZE, 0, stream>>>(packed,
                                                                bucket_start,
                                                                totals, payload,
                                                                out, N);
    } else {
        // R10-measured fallback (global-atomic offsets).
        float4* packed = (float4*)d_ws;
        int* bucket_cnt = (int*)(packed + (size_t)2 * N);
        int* bucket_start = bucket_cnt + NBUCKET_MAX;
        int* cursor = bucket_start + NBUCKET_MAX;
        unsigned* payload = (unsigned*)(cursor + NBUCKET_MAX);

        hipMemsetAsync(bucket_cnt, 0, NBUCKET_MAX * sizeof(int), stream);
        pack_kernel<<<(N + 255) / 256, 256, 0, stream>>>(pos, field, packed, N);
        bucket_count_kernel<<<nblocksF, BTHREADS, 0, stream>>>(rows, bucket_cnt,
                                                               E, nbuckets);
        bucket_scan_kernel<<<1, NBUCKET_MAX, 0, stream>>>(bucket_cnt,
                                                          bucket_start, cursor,
                                                          nbuckets);
        bucket_scatter_kernel<<<nblocksF, BTHREADS, 0, stream>>>(rows, cols,
                                                                 cursor, payload,
                                                                 E, nbuckets);
        // cursor == end after KB; start+cnt == end, so bucket_cnt acts as totals
        bucket_sort_accum_solve<<<nbuckets, BSIZE, 0, stream>>>(packed,
                                                                bucket_start,
                                                                bucket_cnt,
                                                                payload, out, N);
    }
}